// Round 13
// baseline (305.920 us; speedup 1.0000x reference)
//
#include <hip/hip_runtime.h>

// ---------------- helpers ----------------

__device__ __forceinline__ float ldf(const void* p, long long i, int f32) {
    if (f32) return ((const float*)p)[i];
    unsigned int u = ((const unsigned short*)p)[i];
    return __uint_as_float(u << 16);
}
__device__ __forceinline__ float bfl(unsigned int u) { return __uint_as_float(u << 16); }
__device__ __forceinline__ float bfh(unsigned int u) { return __uint_as_float(u & 0xFFFF0000u); }
__device__ __forceinline__ int ld_idx(const int* p, long long i, int i64) {
    return i64 ? p[2 * i] : p[i];   // little-endian low word of int64
}
__device__ __forceinline__ unsigned short f2bf(float v) {
    unsigned int x = __float_as_uint(v);
    return (unsigned short)((x + 0x7FFFu + ((x >> 16) & 1u)) >> 16);  // RNE
}
__device__ __forceinline__ int clampi(int v, int lo, int hi) {
    return v < lo ? lo : (v > hi ? hi : v);
}

// ---------------- weights layout (contiguous f32) ----------------
#define OW1 0
#define OB1 8192
#define OW2 8320
#define OB2 24704
#define OW3 24832
#define OB3 41216
#define OW4 41344
#define OB4 49536
#define OTOT 49600

// ---------------- prep: dtype-detect + zero-init + weight/x convert ----------------
// flags[0]=1 f32 floats / 0 bf16 ; flags[1]=1 int64 / 0 int32 ; flags[8]=done counter

__global__ void gnn_prep(const void* W1, const void* b1, const void* W2, const void* b2,
                         const void* W3, const void* b3, const void* W4, const void* b4,
                         const void* x, const int* __restrict__ ei,
                         int* __restrict__ flags_out,
                         int* __restrict__ degcnt, float* __restrict__ pooled,
                         float* __restrict__ wsW, unsigned short* __restrict__ xb,
                         int N, int B) {
    __shared__ int s_cnt, s_or;
    const int t = threadIdx.x;
    if (t == 0) { s_cnt = 0; s_or = 0; }
    __syncthreads();
    {
        const unsigned int* w1w = (const unsigned int*)W1;
        int c = 0, o = 0;
        for (int i = t; i < 512; i += 256) {
            unsigned int e = (w1w[i] >> 7) & 0xFFu;
            if (e >= 100 && e <= 140) c++;
        }
        for (int i = t; i < 1024; i += 256) o |= ei[2 * i + 1];
        atomicAdd(&s_cnt, c);
        atomicOr(&s_or, o);
    }
    __syncthreads();
    const int f32 = (s_cnt > 256) ? 0 : 1;
    if (blockIdx.x == 0 && t == 0) {
        flags_out[0] = f32;
        flags_out[1] = (s_or == 0) ? 1 : 0;
        flags_out[8] = 0;                      // scan "last block" ticket
    }
    const int i = blockIdx.x * 256 + t;
    const int stride = gridDim.x * 256;
    for (int j = i; j < N; j += stride) degcnt[j] = 0;
    for (int j = i; j < B * 128; j += stride) pooled[j] = 0.f;
    for (int j = i; j < OTOT; j += stride) {
        float v;
        if      (j < OB1) v = ldf(W1, j - OW1, f32);
        else if (j < OW2) v = ldf(b1, j - OB1, f32);
        else if (j < OB2) v = ldf(W2, j - OW2, f32);
        else if (j < OW3) v = ldf(b2, j - OB2, f32);
        else if (j < OB3) v = ldf(W3, j - OW3, f32);
        else if (j < OW4) v = ldf(b3, j - OB3, f32);
        else if (j < OB4) v = ldf(W4, j - OW4, f32);
        else              v = ldf(b4, j - OB4, f32);
        wsW[j] = v;
    }
    if (f32) {
        const float* xf = (const float*)x;
        for (int j = i; j < N * 64; j += stride) xb[j] = f2bf(xf[j]);
    }
}

// ---------------- CSR build ----------------

__global__ void gnn_hist(const int* __restrict__ ei, int E, int N,
                         const int* __restrict__ flags, int* __restrict__ degcnt,
                         int* __restrict__ rank) {
    int base = (blockIdx.x * 256 + threadIdx.x) * 4;
    if (base >= E) return;
    int i64 = flags[1];
    int m = min(4, E - base);
    int d[4], r[4];
#pragma unroll
    for (int j = 0; j < 4; ++j)
        if (j < m) d[j] = clampi(ld_idx(ei, (long long)E + base + j, i64), 0, N - 1);
#pragma unroll
    for (int j = 0; j < 4; ++j)
        if (j < m) r[j] = atomicAdd(&degcnt[d[j]], 1);
#pragma unroll
    for (int j = 0; j < 4; ++j)
        if (j < m) rank[base + j] = r[j];
}

// scan1: per-block exclusive scan + dis; LAST finishing block scans the block sums.
__global__ void gnn_scan1(const int* __restrict__ cnt, int* __restrict__ excl,
                          int* __restrict__ sums, int* __restrict__ bsums,
                          float* __restrict__ dis, int* __restrict__ done,
                          int N, int nb) {
    __shared__ int sh[256];
    __shared__ int isLast;
    int t = threadIdx.x;
    int i = blockIdx.x * 256 + t;
    int v = (i < N) ? cnt[i] : 0;
    sh[t] = v;
    __syncthreads();
    for (int off = 1; off < 256; off <<= 1) {
        int a = (t >= off) ? sh[t - off] : 0;
        __syncthreads();
        sh[t] += a;
        __syncthreads();
    }
    if (i < N) {
        excl[i] = sh[t] - v;
        dis[i] = rsqrtf((float)v + 1.0f);
    }
    if (t == 255) sums[blockIdx.x] = sh[255];
    __threadfence();
    __syncthreads();
    if (t == 0) isLast = (atomicAdd(done, 1) == nb - 1) ? 1 : 0;
    __syncthreads();
    if (!isLast) return;
    int v2 = (t < nb) ? sums[t] : 0;
    sh[t] = v2;
    __syncthreads();
    for (int off = 1; off < 256; off <<= 1) {
        int a = (t >= off) ? sh[t - off] : 0;
        __syncthreads();
        sh[t] += a;
        __syncthreads();
    }
    if (t < nb) bsums[t] = sh[t] - v2;
}

template <bool SMALLN>
__global__ void gnn_fill(const int* __restrict__ ei, const int* __restrict__ excl,
                         const int* __restrict__ bsums, const int* __restrict__ rank,
                         void* __restrict__ csr, int E, int N,
                         const int* __restrict__ flags) {
    int e = blockIdx.x * 256 + threadIdx.x;
    if (e >= E) return;
    int i64 = flags[1];
    int s = clampi(ld_idx(ei, (long long)e, i64), 0, N - 1);
    int d = clampi(ld_idx(ei, (long long)E + e, i64), 0, N - 1);
    int pos = excl[d] + bsums[d >> 8] + rank[e];
    if (SMALLN) ((unsigned short*)csr)[pos] = (unsigned short)s;
    else        ((int*)csr)[pos] = s;
}

template <bool SMALLN>
__device__ __forceinline__ int csr_at(const void* csr, int e) {
    return SMALLN ? (int)((const unsigned short*)csr)[e] : ((const int*)csr)[e];
}

// ---------------- fused layer 1: aggX (LDS) then X@W1+b1 -> relu -> H1 (f32) ----------
// 16 nodes/block, 128 threads. Phase A: 4 passes x (2 nodes/wave x 2 waves),
// 8-wide edge unroll. Phase B: K=64 GEMM, W from L2.

template <bool SMALLN>
__global__ __launch_bounds__(128) void gnn_aggx_lin1(const void* __restrict__ x,
                                                     const unsigned short* __restrict__ xconv,
                                                     const int* __restrict__ excl,
                                                     const int* __restrict__ bsums,
                                                     const void* __restrict__ csr,
                                                     const float* __restrict__ dis,
                                                     const int* __restrict__ flags,
                                                     const float* __restrict__ Wf,
                                                     const float* __restrict__ bias,
                                                     int N, int E, float* __restrict__ out) {
    __shared__ float Xs[16 * 64];   // 4 KB
    const unsigned int* tab = flags[0] ? (const unsigned int*)xconv : (const unsigned int*)x;
    const int t = threadIdx.x;
    const int nbase = blockIdx.x * 16;
    const int lane = t & 63;
    const int fl = lane & 31;

#pragma unroll
    for (int pass = 0; pass < 4; ++pass) {
        int ln = pass * 4 + (t >> 6) * 2 + (lane >> 5);
        int n = nbase + ln;
        float a0 = 0.f, a1 = 0.f;
        if (n < N) {
            float dn = dis[n], dn2 = dn * dn;
            unsigned int us = tab[(long long)n * 32 + fl];
            a0 = bfl(us) * dn2; a1 = bfh(us) * dn2;
            int beg = excl[n] + bsums[n >> 8];
            int end = (n + 1 < N) ? (excl[n + 1] + bsums[(n + 1) >> 8]) : E;
            int e = beg;
            for (; e + 8 <= end; e += 8) {
                int s0 = csr_at<SMALLN>(csr, e),     s1 = csr_at<SMALLN>(csr, e + 1);
                int s2 = csr_at<SMALLN>(csr, e + 2), s3 = csr_at<SMALLN>(csr, e + 3);
                int s4 = csr_at<SMALLN>(csr, e + 4), s5 = csr_at<SMALLN>(csr, e + 5);
                int s6 = csr_at<SMALLN>(csr, e + 6), s7 = csr_at<SMALLN>(csr, e + 7);
                float w0 = dis[s0], w1 = dis[s1], w2 = dis[s2], w3 = dis[s3];
                float w4 = dis[s4], w5 = dis[s5], w6 = dis[s6], w7 = dis[s7];
                unsigned int u0 = tab[(long long)s0 * 32 + fl];
                unsigned int u1 = tab[(long long)s1 * 32 + fl];
                unsigned int u2 = tab[(long long)s2 * 32 + fl];
                unsigned int u3 = tab[(long long)s3 * 32 + fl];
                unsigned int u4 = tab[(long long)s4 * 32 + fl];
                unsigned int u5 = tab[(long long)s5 * 32 + fl];
                unsigned int u6 = tab[(long long)s6 * 32 + fl];
                unsigned int u7 = tab[(long long)s7 * 32 + fl];
                w0 *= dn; w1 *= dn; w2 *= dn; w3 *= dn;
                w4 *= dn; w5 *= dn; w6 *= dn; w7 *= dn;
                a0 = fmaf(w0, bfl(u0), a0); a1 = fmaf(w0, bfh(u0), a1);
                a0 = fmaf(w1, bfl(u1), a0); a1 = fmaf(w1, bfh(u1), a1);
                a0 = fmaf(w2, bfl(u2), a0); a1 = fmaf(w2, bfh(u2), a1);
                a0 = fmaf(w3, bfl(u3), a0); a1 = fmaf(w3, bfh(u3), a1);
                a0 = fmaf(w4, bfl(u4), a0); a1 = fmaf(w4, bfh(u4), a1);
                a0 = fmaf(w5, bfl(u5), a0); a1 = fmaf(w5, bfh(u5), a1);
                a0 = fmaf(w6, bfl(u6), a0); a1 = fmaf(w6, bfh(u6), a1);
                a0 = fmaf(w7, bfl(u7), a0); a1 = fmaf(w7, bfh(u7), a1);
            }
            for (; e + 4 <= end; e += 4) {
                int s0 = csr_at<SMALLN>(csr, e),     s1 = csr_at<SMALLN>(csr, e + 1);
                int s2 = csr_at<SMALLN>(csr, e + 2), s3 = csr_at<SMALLN>(csr, e + 3);
                float w0 = dis[s0], w1 = dis[s1], w2 = dis[s2], w3 = dis[s3];
                unsigned int u0 = tab[(long long)s0 * 32 + fl];
                unsigned int u1 = tab[(long long)s1 * 32 + fl];
                unsigned int u2 = tab[(long long)s2 * 32 + fl];
                unsigned int u3 = tab[(long long)s3 * 32 + fl];
                w0 *= dn; w1 *= dn; w2 *= dn; w3 *= dn;
                a0 = fmaf(w0, bfl(u0), a0); a1 = fmaf(w0, bfh(u0), a1);
                a0 = fmaf(w1, bfl(u1), a0); a1 = fmaf(w1, bfh(u1), a1);
                a0 = fmaf(w2, bfl(u2), a0); a1 = fmaf(w2, bfh(u2), a1);
                a0 = fmaf(w3, bfl(u3), a0); a1 = fmaf(w3, bfh(u3), a1);
            }
            for (; e < end; ++e) {
                int s = csr_at<SMALLN>(csr, e);
                float w = dis[s] * dn;
                unsigned int u = tab[(long long)s * 32 + fl];
                a0 = fmaf(w, bfl(u), a0); a1 = fmaf(w, bfh(u), a1);
            }
        }
        Xs[ln * 64 + fl * 2]     = a0;
        Xs[ln * 64 + fl * 2 + 1] = a1;
    }
    __syncthreads();

    const int fg = t & 31, ng = t >> 5;
    const int f0 = fg * 4, n0 = ng * 4;
    const float4* Xs4 = (const float4*)Xs;       // [node][16]
    const float4* Wp  = (const float4*)Wf;       // [k][32]
    float4 acc[4];
#pragma unroll
    for (int j = 0; j < 4; ++j) acc[j] = make_float4(0.f, 0.f, 0.f, 0.f);
#pragma unroll 4
    for (int k4 = 0; k4 < 16; ++k4) {
        const float4 wa = Wp[(4 * k4 + 0) * 32 + fg];
        const float4 wb = Wp[(4 * k4 + 1) * 32 + fg];
        const float4 wc = Wp[(4 * k4 + 2) * 32 + fg];
        const float4 wd = Wp[(4 * k4 + 3) * 32 + fg];
#pragma unroll
        for (int j = 0; j < 4; ++j) {
            const float4 xv = Xs4[(n0 + j) * 16 + k4];
            acc[j].x = fmaf(xv.x, wa.x, acc[j].x); acc[j].y = fmaf(xv.x, wa.y, acc[j].y);
            acc[j].z = fmaf(xv.x, wa.z, acc[j].z); acc[j].w = fmaf(xv.x, wa.w, acc[j].w);
            acc[j].x = fmaf(xv.y, wb.x, acc[j].x); acc[j].y = fmaf(xv.y, wb.y, acc[j].y);
            acc[j].z = fmaf(xv.y, wb.z, acc[j].z); acc[j].w = fmaf(xv.y, wb.w, acc[j].w);
            acc[j].x = fmaf(xv.z, wc.x, acc[j].x); acc[j].y = fmaf(xv.z, wc.y, acc[j].y);
            acc[j].z = fmaf(xv.z, wc.z, acc[j].z); acc[j].w = fmaf(xv.z, wc.w, acc[j].w);
            acc[j].x = fmaf(xv.w, wd.x, acc[j].x); acc[j].y = fmaf(xv.w, wd.y, acc[j].y);
            acc[j].z = fmaf(xv.w, wd.z, acc[j].z); acc[j].w = fmaf(xv.w, wd.w, acc[j].w);
        }
    }
    const float4 b = *(const float4*)&bias[f0];
#pragma unroll
    for (int j = 0; j < 4; ++j) {
        int n = nbase + n0 + j;
        if (n >= N) continue;
        float4 a = acc[j];
        a.x = fmaxf(a.x + b.x, 0.f);
        a.y = fmaxf(a.y + b.y, 0.f);
        a.z = fmaxf(a.z + b.z, 0.f);
        a.w = fmaxf(a.w + b.w, 0.f);
        *(float4*)(out + (long long)n * 128 + f0) = a;
    }
}

// ---------------- Linear (layer 2): A2 = H1 @ W2 (bf16 out); 16 nodes / 128 thr ------

template <int K, bool RELU, bool OUTBF>
__global__ __launch_bounds__(128) void gnn_linear(const float* __restrict__ X,
                                                  const float* __restrict__ Wf,
                                                  const float* __restrict__ bias,
                                                  int N, void* __restrict__ out) {
    __shared__ float Xs[16 * K];
    const int t = threadIdx.x;
    const int nbase = blockIdx.x * 16;

#pragma unroll
    for (int it = 0; it < K / 32; ++it) {
        int i4 = t + it * 128;
        int n = nbase + (i4 * 4) / K;
        float4 v = make_float4(0.f, 0.f, 0.f, 0.f);
        if (n < N) v = ((const float4*)X)[(long long)nbase * (K / 4) + i4];
        ((float4*)Xs)[i4] = v;
    }
    __syncthreads();

    const int fg = t & 31, ng = t >> 5;
    const int f0 = fg * 4, n0 = ng * 4;
    const float4* Xs4 = (const float4*)Xs;            // [node][K/4]
    const float4* Wp  = (const float4*)Wf;            // [k][32]
    float4 acc[4];
#pragma unroll
    for (int j = 0; j < 4; ++j) acc[j] = make_float4(0.f, 0.f, 0.f, 0.f);
#pragma unroll 4
    for (int k4 = 0; k4 < K / 4; ++k4) {
        const float4 wa = Wp[(4 * k4 + 0) * 32 + fg];
        const float4 wb = Wp[(4 * k4 + 1) * 32 + fg];
        const float4 wc = Wp[(4 * k4 + 2) * 32 + fg];
        const float4 wd = Wp[(4 * k4 + 3) * 32 + fg];
#pragma unroll
        for (int j = 0; j < 4; ++j) {
            const float4 xv = Xs4[(n0 + j) * (K / 4) + k4];
            acc[j].x = fmaf(xv.x, wa.x, acc[j].x); acc[j].y = fmaf(xv.x, wa.y, acc[j].y);
            acc[j].z = fmaf(xv.x, wa.z, acc[j].z); acc[j].w = fmaf(xv.x, wa.w, acc[j].w);
            acc[j].x = fmaf(xv.y, wb.x, acc[j].x); acc[j].y = fmaf(xv.y, wb.y, acc[j].y);
            acc[j].z = fmaf(xv.y, wb.z, acc[j].z); acc[j].w = fmaf(xv.y, wb.w, acc[j].w);
            acc[j].x = fmaf(xv.z, wc.x, acc[j].x); acc[j].y = fmaf(xv.z, wc.y, acc[j].y);
            acc[j].z = fmaf(xv.z, wc.z, acc[j].z); acc[j].w = fmaf(xv.z, wc.w, acc[j].w);
            acc[j].x = fmaf(xv.w, wd.x, acc[j].x); acc[j].y = fmaf(xv.w, wd.y, acc[j].y);
            acc[j].z = fmaf(xv.w, wd.z, acc[j].z); acc[j].w = fmaf(xv.w, wd.w, acc[j].w);
        }
    }
#pragma unroll
    for (int j = 0; j < 4; ++j) {
        int n = nbase + n0 + j;
        if (n >= N) continue;
        float4 a = acc[j];
        if (RELU) {
            const float4 b = *(const float4*)&bias[f0];
            a.x = fmaxf(a.x + b.x, 0.f);
            a.y = fmaxf(a.y + b.y, 0.f);
            a.z = fmaxf(a.z + b.z, 0.f);
            a.w = fmaxf(a.w + b.w, 0.f);
        }
        if (OUTBF) {
            uint2 u;
            u.x = (unsigned int)f2bf(a.x) | ((unsigned int)f2bf(a.y) << 16);
            u.y = (unsigned int)f2bf(a.z) | ((unsigned int)f2bf(a.w) << 16);
            *(uint2*)((unsigned short*)out + (long long)n * 128 + f0) = u;
        } else {
            *(float4*)((float*)out + (long long)n * 128 + f0) = a;
        }
    }
}

// ---------------- Layer-2 aggregation, feature-quartered + XCD-pinned ----------------
// Block b: quarter q=(b&7)>>1 (pinned to an XCD pair via blockIdx%8 round-robin),
// node-group g=(b>>3)*2+(b&1). 256 thr: 16 nodes, 16 lanes/node, lane = 2 feats (uint).
// Per-XCD working set = 3.2 MB quarter of A2 -> L2-resident. 8-wide edge unroll.

template <bool SMALLN>
__global__ __launch_bounds__(256) void gnn_agg_q(const unsigned short* __restrict__ A2,
                                                 const int* __restrict__ excl,
                                                 const int* __restrict__ bsums,
                                                 const void* __restrict__ csr,
                                                 const float* __restrict__ dis,
                                                 const float* __restrict__ bias,
                                                 float* __restrict__ outC, int N, int E) {
    const int b = blockIdx.x;
    const int q = (b & 7) >> 1;
    const int g = (b >> 3) * 2 + (b & 1);
    const int t = threadIdx.x;
    const int n = g * 16 + (t >> 4);
    if (n >= N) return;
    const int fo = q * 32 + (t & 15) * 2;        // this lane's feature pair
    float dn = dis[n];
    float dn2 = dn * dn;
    unsigned int us = *(const unsigned int*)(A2 + (long long)n * 128 + fo);
    float a0 = bfl(us) * dn2, a1 = bfh(us) * dn2;
    int beg = excl[n] + bsums[n >> 8];
    int end = (n + 1 < N) ? (excl[n + 1] + bsums[(n + 1) >> 8]) : E;
    int e = beg;
    for (; e + 8 <= end; e += 8) {
        int s0 = csr_at<SMALLN>(csr, e),     s1 = csr_at<SMALLN>(csr, e + 1);
        int s2 = csr_at<SMALLN>(csr, e + 2), s3 = csr_at<SMALLN>(csr, e + 3);
        int s4 = csr_at<SMALLN>(csr, e + 4), s5 = csr_at<SMALLN>(csr, e + 5);
        int s6 = csr_at<SMALLN>(csr, e + 6), s7 = csr_at<SMALLN>(csr, e + 7);
        float w0 = dis[s0], w1 = dis[s1], w2 = dis[s2], w3 = dis[s3];
        float w4 = dis[s4], w5 = dis[s5], w6 = dis[s6], w7 = dis[s7];
        unsigned int u0 = *(const unsigned int*)(A2 + (long long)s0 * 128 + fo);
        unsigned int u1 = *(const unsigned int*)(A2 + (long long)s1 * 128 + fo);
        unsigned int u2 = *(const unsigned int*)(A2 + (long long)s2 * 128 + fo);
        unsigned int u3 = *(const unsigned int*)(A2 + (long long)s3 * 128 + fo);
        unsigned int u4 = *(const unsigned int*)(A2 + (long long)s4 * 128 + fo);
        unsigned int u5 = *(const unsigned int*)(A2 + (long long)s5 * 128 + fo);
        unsigned int u6 = *(const unsigned int*)(A2 + (long long)s6 * 128 + fo);
        unsigned int u7 = *(const unsigned int*)(A2 + (long long)s7 * 128 + fo);
        w0 *= dn; w1 *= dn; w2 *= dn; w3 *= dn;
        w4 *= dn; w5 *= dn; w6 *= dn; w7 *= dn;
        a0 = fmaf(w0, bfl(u0), a0); a1 = fmaf(w0, bfh(u0), a1);
        a0 = fmaf(w1, bfl(u1), a0); a1 = fmaf(w1, bfh(u1), a1);
        a0 = fmaf(w2, bfl(u2), a0); a1 = fmaf(w2, bfh(u2), a1);
        a0 = fmaf(w3, bfl(u3), a0); a1 = fmaf(w3, bfh(u3), a1);
        a0 = fmaf(w4, bfl(u4), a0); a1 = fmaf(w4, bfh(u4), a1);
        a0 = fmaf(w5, bfl(u5), a0); a1 = fmaf(w5, bfh(u5), a1);
        a0 = fmaf(w6, bfl(u6), a0); a1 = fmaf(w6, bfh(u6), a1);
        a0 = fmaf(w7, bfl(u7), a0); a1 = fmaf(w7, bfh(u7), a1);
    }
    for (; e + 4 <= end; e += 4) {
        int s0 = csr_at<SMALLN>(csr, e),     s1 = csr_at<SMALLN>(csr, e + 1);
        int s2 = csr_at<SMALLN>(csr, e + 2), s3 = csr_at<SMALLN>(csr, e + 3);
        float w0 = dis[s0], w1 = dis[s1], w2 = dis[s2], w3 = dis[s3];
        unsigned int u0 = *(const unsigned int*)(A2 + (long long)s0 * 128 + fo);
        unsigned int u1 = *(const unsigned int*)(A2 + (long long)s1 * 128 + fo);
        unsigned int u2 = *(const unsigned int*)(A2 + (long long)s2 * 128 + fo);
        unsigned int u3 = *(const unsigned int*)(A2 + (long long)s3 * 128 + fo);
        w0 *= dn; w1 *= dn; w2 *= dn; w3 *= dn;
        a0 = fmaf(w0, bfl(u0), a0); a1 = fmaf(w0, bfh(u0), a1);
        a0 = fmaf(w1, bfl(u1), a0); a1 = fmaf(w1, bfh(u1), a1);
        a0 = fmaf(w2, bfl(u2), a0); a1 = fmaf(w2, bfh(u2), a1);
        a0 = fmaf(w3, bfl(u3), a0); a1 = fmaf(w3, bfh(u3), a1);
    }
    for (; e < end; ++e) {
        int s = csr_at<SMALLN>(csr, e);
        float w = dis[s] * dn;
        unsigned int u = *(const unsigned int*)(A2 + (long long)s * 128 + fo);
        a0 = fmaf(w, bfl(u), a0); a1 = fmaf(w, bfh(u), a1);
    }
    float2 o;
    o.x = fmaxf(a0 + bias[fo], 0.f);
    o.y = fmaxf(a1 + bias[fo + 1], 0.f);
    *(float2*)(outC + (long long)n * 128 + fo) = o;
}

// ---------------- Pool (batch sorted): 32-node strips, pre-reduced atomic flush -------

#define PSTRIP 32
__global__ __launch_bounds__(128) void gnn_pool(const float* __restrict__ h,
                                                const int* __restrict__ batch,
                                                const int* __restrict__ flags,
                                                float* __restrict__ pooled, int N, int B) {
    int i64 = flags[1];
    int f = threadIdx.x;
    int n0 = blockIdx.x * PSTRIP;
    if (n0 >= N) return;
    int nend = min(n0 + PSTRIP, N);
    int cur = clampi(ld_idx(batch, n0, i64), 0, B - 1);
    float acc = 0.0f;
    for (int n = n0; n < nend; ++n) {
        int b = clampi(ld_idx(batch, n, i64), 0, B - 1);
        if (b != cur) {
            atomicAdd(&pooled[cur * 128 + f], acc);
            acc = 0.0f; cur = b;
        }
        acc += h[(long long)n * 128 + f];
    }
    atomicAdd(&pooled[cur * 128 + f], acc);
}

// ---------------- head: mean (cnt via binary search) + MLP ----------------

__global__ __launch_bounds__(128) void gnn_head(const float* __restrict__ pooled,
                                                const int* __restrict__ batch,
                                                const float* __restrict__ W3,
                                                const float* __restrict__ b3,
                                                const float* __restrict__ W4,
                                                const float* __restrict__ b4,
                                                const int* __restrict__ flags,
                                                void* __restrict__ outv, int N) {
    __shared__ float xs[128];
    __shared__ float rs[128];
    __shared__ float cinv;
    int b = blockIdx.x, f = threadIdx.x;
    if (f == 0) {
        int i64 = flags[1];
        int L = 0, R = N;
        while (L < R) { int m = (L + R) >> 1; if (ld_idx(batch, m, i64) < b) L = m + 1; else R = m; }
        int lo = L;
        L = 0; R = N;
        while (L < R) { int m = (L + R) >> 1; if (ld_idx(batch, m, i64) < b + 1) L = m + 1; else R = m; }
        cinv = 1.0f / fmaxf((float)(L - lo), 1.0f);
    }
    __syncthreads();
    xs[f] = pooled[b * 128 + f] * cinv;
    __syncthreads();
    float acc = b3[f];
    for (int k = 0; k < 128; ++k) acc = fmaf(xs[k], W3[k * 128 + f], acc);
    rs[f] = fmaxf(acc, 0.f);
    __syncthreads();
    if (f < 64) {
        float a2 = b4[f];
        for (int k = 0; k < 128; ++k) a2 = fmaf(rs[k], W4[k * 64 + f], a2);
        if (flags[0]) ((float*)outv)[b * 64 + f] = a2;
        else          ((unsigned short*)outv)[b * 64 + f] = f2bf(a2);
    }
}

// ---------------- Launch ----------------

extern "C" void kernel_launch(void* const* d_in, const int* in_sizes, int n_in,
                              void* d_out, int out_size, void* d_ws, size_t ws_size,
                              hipStream_t stream) {
    const void* x  = d_in[0];
    const int* ei  = (const int*)d_in[1];
    const int* bat = (const int*)d_in[2];

    const int N = in_sizes[0] / 64;    // 50000
    const int E = in_sizes[1] / 2;     // 800000
    const int B = out_size / 64;       // 64
    const bool smalln = (N < 65536);

    char* p = (char*)d_ws;
    auto alloc = [&](size_t bytes) { void* q = (void*)p; p += (bytes + 255) & ~(size_t)255; return q; };
    int*   flags    = (int*)alloc(256);
    float* wsW      = (float*)alloc((size_t)OTOT * 4);
    int*   degcnt   = (int*)alloc((size_t)N * 4);
    float* dis      = (float*)alloc((size_t)N * 4);
    int*   excl     = (int*)alloc((size_t)N * 4);
    int*   sums     = (int*)alloc(1024);
    int*   bsums    = (int*)alloc(1024);
    int*   rank     = (int*)alloc((size_t)E * 4);
    void*  csr      = alloc((size_t)E * (smalln ? 2 : 4));
    unsigned short* xb = (unsigned short*)alloc((size_t)N * 64 * 2);
    float* H1       = (float*)alloc((size_t)N * 128 * 4);
    float* C2       = (float*)alloc((size_t)N * 128 * 4);
    unsigned short* A2 = (unsigned short*)alloc((size_t)N * 128 * 2);
    float* pooled   = (float*)alloc((size_t)B * 128 * 4);
    (void)ws_size; (void)n_in;

    const int nbN = (N + 255) / 256;   // 196 (<=256 for last-block scan)

    gnn_prep<<<512, 256, 0, stream>>>(d_in[3], d_in[4], d_in[5], d_in[6],
                                      d_in[7], d_in[8], d_in[9], d_in[10],
                                      x, ei, flags, degcnt, pooled, wsW, xb, N, B);

    gnn_hist<<<(E + 1023) / 1024, 256, 0, stream>>>(ei, E, N, flags, degcnt, rank);
    gnn_scan1<<<nbN, 256, 0, stream>>>(degcnt, excl, sums, bsums, dis, flags + 8, N, nbN);
    if (smalln)
        gnn_fill<true><<<(E + 255) / 256, 256, 0, stream>>>(ei, excl, bsums, rank, csr, E, N, flags);
    else
        gnn_fill<false><<<(E + 255) / 256, 256, 0, stream>>>(ei, excl, bsums, rank, csr, E, N, flags);

    const int nlin = (N + 15) / 16;    // 16-node blocks, 128 threads

    // layer 1 (fused): H1 = relu((A_hat @ x) @ W1 + b1)
    if (smalln)
        gnn_aggx_lin1<true><<<nlin, 128, 0, stream>>>(x, xb, excl, bsums, csr, dis, flags,
                                                      wsW + OW1, wsW + OB1, N, E, H1);
    else
        gnn_aggx_lin1<false><<<nlin, 128, 0, stream>>>(x, xb, excl, bsums, csr, dis, flags,
                                                       wsW + OW1, wsW + OB1, N, E, H1);

    // layer 2: A2 = H1 @ W2 (bf16) ; C2 = relu(A_hat @ A2 + b2) quarter-split
    gnn_linear<128, false, true><<<nlin, 128, 0, stream>>>(H1, wsW + OW2, wsW + OB2, N, (void*)A2);
    const int nb8 = ((nlin /*=ceil(N/16)*/) + 1) / 2;   // node-group pairs
    const int naggq = nb8 * 8;                           // 4 quarters x XCD-pinned pairs
    if (smalln)
        gnn_agg_q<true><<<naggq, 256, 0, stream>>>(A2, excl, bsums, csr, dis, wsW + OB2, C2, N, E);
    else
        gnn_agg_q<false><<<naggq, 256, 0, stream>>>(A2, excl, bsums, csr, dis, wsW + OB2, C2, N, E);

    // pool + head
    gnn_pool<<<(N + PSTRIP - 1) / PSTRIP, 128, 0, stream>>>(C2, bat, flags, pooled, N, B);
    gnn_head<<<B, 128, 0, stream>>>(pooled, bat, wsW + OW3, wsW + OB3,
                                    wsW + OW4, wsW + OB4, flags, d_out, N);
}

// Round 14
// 289.415 us; speedup vs baseline: 1.0570x; 1.0570x over previous
//
#include <hip/hip_runtime.h>

// ---------------- helpers ----------------

__device__ __forceinline__ float ldf(const void* p, long long i, int f32) {
    if (f32) return ((const float*)p)[i];
    unsigned int u = ((const unsigned short*)p)[i];
    return __uint_as_float(u << 16);
}
__device__ __forceinline__ float bfl(unsigned int u) { return __uint_as_float(u << 16); }
__device__ __forceinline__ float bfh(unsigned int u) { return __uint_as_float(u & 0xFFFF0000u); }
__device__ __forceinline__ int ld_idx(const int* p, long long i, int i64) {
    return i64 ? p[2 * i] : p[i];   // little-endian low word of int64
}
__device__ __forceinline__ unsigned short f2bf(float v) {
    unsigned int x = __float_as_uint(v);
    return (unsigned short)((x + 0x7FFFu + ((x >> 16) & 1u)) >> 16);  // RNE
}
__device__ __forceinline__ int clampi(int v, int lo, int hi) {
    return v < lo ? lo : (v > hi ? hi : v);
}

// ---------------- weights layout (contiguous f32) ----------------
#define OW1 0
#define OB1 8192
#define OW2 8320
#define OB2 24704
#define OW3 24832
#define OB3 41216
#define OW4 41344
#define OB4 49536
#define OTOT 49600

// ---------------- prep: dtype-detect + zero-init + weight/x convert ----------------
// flags[0]=1 f32 floats / 0 bf16 ; flags[1]=1 int64 / 0 int32 ; flags[8]=done counter

__global__ void gnn_prep(const void* W1, const void* b1, const void* W2, const void* b2,
                         const void* W3, const void* b3, const void* W4, const void* b4,
                         const void* x, const int* __restrict__ ei,
                         int* __restrict__ flags_out,
                         int* __restrict__ degcnt, float* __restrict__ pooled,
                         float* __restrict__ wsW, unsigned short* __restrict__ xb,
                         int N, int B) {
    __shared__ int s_cnt, s_or;
    const int t = threadIdx.x;
    if (t == 0) { s_cnt = 0; s_or = 0; }
    __syncthreads();
    {
        const unsigned int* w1w = (const unsigned int*)W1;
        int c = 0, o = 0;
        for (int i = t; i < 512; i += 256) {
            unsigned int e = (w1w[i] >> 7) & 0xFFu;
            if (e >= 100 && e <= 140) c++;
        }
        for (int i = t; i < 1024; i += 256) o |= ei[2 * i + 1];
        atomicAdd(&s_cnt, c);
        atomicOr(&s_or, o);
    }
    __syncthreads();
    const int f32 = (s_cnt > 256) ? 0 : 1;
    if (blockIdx.x == 0 && t == 0) {
        flags_out[0] = f32;
        flags_out[1] = (s_or == 0) ? 1 : 0;
        flags_out[8] = 0;                      // scan "last block" ticket
    }
    const int i = blockIdx.x * 256 + t;
    const int stride = gridDim.x * 256;
    for (int j = i; j < N; j += stride) degcnt[j] = 0;
    for (int j = i; j < B * 128; j += stride) pooled[j] = 0.f;
    for (int j = i; j < OTOT; j += stride) {
        float v;
        if      (j < OB1) v = ldf(W1, j - OW1, f32);
        else if (j < OW2) v = ldf(b1, j - OB1, f32);
        else if (j < OB2) v = ldf(W2, j - OW2, f32);
        else if (j < OW3) v = ldf(b2, j - OB2, f32);
        else if (j < OB3) v = ldf(W3, j - OW3, f32);
        else if (j < OW4) v = ldf(b3, j - OB3, f32);
        else if (j < OB4) v = ldf(W4, j - OW4, f32);
        else              v = ldf(b4, j - OB4, f32);
        wsW[j] = v;
    }
    if (f32) {
        const float* xf = (const float*)x;
        for (int j = i; j < N * 64; j += stride) xb[j] = f2bf(xf[j]);
    }
}

// ---------------- CSR build ----------------

__global__ void gnn_hist(const int* __restrict__ ei, int E, int N,
                         const int* __restrict__ flags, int* __restrict__ degcnt,
                         int* __restrict__ rank) {
    int base = (blockIdx.x * 256 + threadIdx.x) * 4;
    if (base >= E) return;
    int i64 = flags[1];
    int m = min(4, E - base);
    int d[4], r[4];
#pragma unroll
    for (int j = 0; j < 4; ++j)
        if (j < m) d[j] = clampi(ld_idx(ei, (long long)E + base + j, i64), 0, N - 1);
#pragma unroll
    for (int j = 0; j < 4; ++j)
        if (j < m) r[j] = atomicAdd(&degcnt[d[j]], 1);
#pragma unroll
    for (int j = 0; j < 4; ++j)
        if (j < m) rank[base + j] = r[j];
}

// scan1: per-block exclusive scan + dis; LAST finishing block scans the block sums.
__global__ void gnn_scan1(const int* __restrict__ cnt, int* __restrict__ excl,
                          int* __restrict__ sums, int* __restrict__ bsums,
                          float* __restrict__ dis, int* __restrict__ done,
                          int N, int nb) {
    __shared__ int sh[256];
    __shared__ int isLast;
    int t = threadIdx.x;
    int i = blockIdx.x * 256 + t;
    int v = (i < N) ? cnt[i] : 0;
    sh[t] = v;
    __syncthreads();
    for (int off = 1; off < 256; off <<= 1) {
        int a = (t >= off) ? sh[t - off] : 0;
        __syncthreads();
        sh[t] += a;
        __syncthreads();
    }
    if (i < N) {
        excl[i] = sh[t] - v;
        dis[i] = rsqrtf((float)v + 1.0f);
    }
    if (t == 255) sums[blockIdx.x] = sh[255];
    __threadfence();
    __syncthreads();
    if (t == 0) isLast = (atomicAdd(done, 1) == nb - 1) ? 1 : 0;
    __syncthreads();
    if (!isLast) return;
    int v2 = (t < nb) ? sums[t] : 0;
    sh[t] = v2;
    __syncthreads();
    for (int off = 1; off < 256; off <<= 1) {
        int a = (t >= off) ? sh[t - off] : 0;
        __syncthreads();
        sh[t] += a;
        __syncthreads();
    }
    if (t < nb) bsums[t] = sh[t] - v2;
}

// fill: atomic-free (rank-based), 4 edges/thread for MLP.
template <bool SMALLN>
__global__ void gnn_fill(const int* __restrict__ ei, const int* __restrict__ excl,
                         const int* __restrict__ bsums, const int* __restrict__ rank,
                         void* __restrict__ csr, int E, int N,
                         const int* __restrict__ flags) {
    int base = (blockIdx.x * 256 + threadIdx.x) * 4;
    if (base >= E) return;
    int i64 = flags[1];
    int m = min(4, E - base);
    int s[4], d[4], pos[4];
#pragma unroll
    for (int j = 0; j < 4; ++j)
        if (j < m) {
            s[j] = clampi(ld_idx(ei, (long long)base + j, i64), 0, N - 1);
            d[j] = clampi(ld_idx(ei, (long long)E + base + j, i64), 0, N - 1);
        }
#pragma unroll
    for (int j = 0; j < 4; ++j)
        if (j < m) pos[j] = excl[d[j]] + bsums[d[j] >> 8] + rank[base + j];
#pragma unroll
    for (int j = 0; j < 4; ++j)
        if (j < m) {
            if (SMALLN) ((unsigned short*)csr)[pos[j]] = (unsigned short)s[j];
            else        ((int*)csr)[pos[j]] = s[j];
        }
}

template <bool SMALLN>
__device__ __forceinline__ int csr_at(const void* csr, int e) {
    return SMALLN ? (int)((const unsigned short*)csr)[e] : ((const int*)csr)[e];
}

// ---------------- fused layer 1: aggX (LDS) then X@W1+b1 -> relu -> H1 (f32) ----------
// 16 nodes/block, 128 threads. Phase A: 4 passes x (2 nodes/wave x 2 waves),
// 8-wide edge unroll. Phase B: K=64 GEMM, W from L2.

template <bool SMALLN>
__global__ __launch_bounds__(128) void gnn_aggx_lin1(const void* __restrict__ x,
                                                     const unsigned short* __restrict__ xconv,
                                                     const int* __restrict__ excl,
                                                     const int* __restrict__ bsums,
                                                     const void* __restrict__ csr,
                                                     const float* __restrict__ dis,
                                                     const int* __restrict__ flags,
                                                     const float* __restrict__ Wf,
                                                     const float* __restrict__ bias,
                                                     int N, int E, float* __restrict__ out) {
    __shared__ float Xs[16 * 64];   // 4 KB
    const unsigned int* tab = flags[0] ? (const unsigned int*)xconv : (const unsigned int*)x;
    const int t = threadIdx.x;
    const int nbase = blockIdx.x * 16;
    const int lane = t & 63;
    const int fl = lane & 31;

#pragma unroll
    for (int pass = 0; pass < 4; ++pass) {
        int ln = pass * 4 + (t >> 6) * 2 + (lane >> 5);
        int n = nbase + ln;
        float a0 = 0.f, a1 = 0.f;
        if (n < N) {
            float dn = dis[n], dn2 = dn * dn;
            unsigned int us = tab[(long long)n * 32 + fl];
            a0 = bfl(us) * dn2; a1 = bfh(us) * dn2;
            int beg = excl[n] + bsums[n >> 8];
            int end = (n + 1 < N) ? (excl[n + 1] + bsums[(n + 1) >> 8]) : E;
            int e = beg;
            for (; e + 8 <= end; e += 8) {
                int s0 = csr_at<SMALLN>(csr, e),     s1 = csr_at<SMALLN>(csr, e + 1);
                int s2 = csr_at<SMALLN>(csr, e + 2), s3 = csr_at<SMALLN>(csr, e + 3);
                int s4 = csr_at<SMALLN>(csr, e + 4), s5 = csr_at<SMALLN>(csr, e + 5);
                int s6 = csr_at<SMALLN>(csr, e + 6), s7 = csr_at<SMALLN>(csr, e + 7);
                float w0 = dis[s0], w1 = dis[s1], w2 = dis[s2], w3 = dis[s3];
                float w4 = dis[s4], w5 = dis[s5], w6 = dis[s6], w7 = dis[s7];
                unsigned int u0 = tab[(long long)s0 * 32 + fl];
                unsigned int u1 = tab[(long long)s1 * 32 + fl];
                unsigned int u2 = tab[(long long)s2 * 32 + fl];
                unsigned int u3 = tab[(long long)s3 * 32 + fl];
                unsigned int u4 = tab[(long long)s4 * 32 + fl];
                unsigned int u5 = tab[(long long)s5 * 32 + fl];
                unsigned int u6 = tab[(long long)s6 * 32 + fl];
                unsigned int u7 = tab[(long long)s7 * 32 + fl];
                w0 *= dn; w1 *= dn; w2 *= dn; w3 *= dn;
                w4 *= dn; w5 *= dn; w6 *= dn; w7 *= dn;
                a0 = fmaf(w0, bfl(u0), a0); a1 = fmaf(w0, bfh(u0), a1);
                a0 = fmaf(w1, bfl(u1), a0); a1 = fmaf(w1, bfh(u1), a1);
                a0 = fmaf(w2, bfl(u2), a0); a1 = fmaf(w2, bfh(u2), a1);
                a0 = fmaf(w3, bfl(u3), a0); a1 = fmaf(w3, bfh(u3), a1);
                a0 = fmaf(w4, bfl(u4), a0); a1 = fmaf(w4, bfh(u4), a1);
                a0 = fmaf(w5, bfl(u5), a0); a1 = fmaf(w5, bfh(u5), a1);
                a0 = fmaf(w6, bfl(u6), a0); a1 = fmaf(w6, bfh(u6), a1);
                a0 = fmaf(w7, bfl(u7), a0); a1 = fmaf(w7, bfh(u7), a1);
            }
            for (; e + 4 <= end; e += 4) {
                int s0 = csr_at<SMALLN>(csr, e),     s1 = csr_at<SMALLN>(csr, e + 1);
                int s2 = csr_at<SMALLN>(csr, e + 2), s3 = csr_at<SMALLN>(csr, e + 3);
                float w0 = dis[s0], w1 = dis[s1], w2 = dis[s2], w3 = dis[s3];
                unsigned int u0 = tab[(long long)s0 * 32 + fl];
                unsigned int u1 = tab[(long long)s1 * 32 + fl];
                unsigned int u2 = tab[(long long)s2 * 32 + fl];
                unsigned int u3 = tab[(long long)s3 * 32 + fl];
                w0 *= dn; w1 *= dn; w2 *= dn; w3 *= dn;
                a0 = fmaf(w0, bfl(u0), a0); a1 = fmaf(w0, bfh(u0), a1);
                a0 = fmaf(w1, bfl(u1), a0); a1 = fmaf(w1, bfh(u1), a1);
                a0 = fmaf(w2, bfl(u2), a0); a1 = fmaf(w2, bfh(u2), a1);
                a0 = fmaf(w3, bfl(u3), a0); a1 = fmaf(w3, bfh(u3), a1);
            }
            for (; e < end; ++e) {
                int s = csr_at<SMALLN>(csr, e);
                float w = dis[s] * dn;
                unsigned int u = tab[(long long)s * 32 + fl];
                a0 = fmaf(w, bfl(u), a0); a1 = fmaf(w, bfh(u), a1);
            }
        }
        Xs[ln * 64 + fl * 2]     = a0;
        Xs[ln * 64 + fl * 2 + 1] = a1;
    }
    __syncthreads();

    const int fg = t & 31, ng = t >> 5;
    const int f0 = fg * 4, n0 = ng * 4;
    const float4* Xs4 = (const float4*)Xs;       // [node][16]
    const float4* Wp  = (const float4*)Wf;       // [k][32]
    float4 acc[4];
#pragma unroll
    for (int j = 0; j < 4; ++j) acc[j] = make_float4(0.f, 0.f, 0.f, 0.f);
#pragma unroll 4
    for (int k4 = 0; k4 < 16; ++k4) {
        const float4 wa = Wp[(4 * k4 + 0) * 32 + fg];
        const float4 wb = Wp[(4 * k4 + 1) * 32 + fg];
        const float4 wc = Wp[(4 * k4 + 2) * 32 + fg];
        const float4 wd = Wp[(4 * k4 + 3) * 32 + fg];
#pragma unroll
        for (int j = 0; j < 4; ++j) {
            const float4 xv = Xs4[(n0 + j) * 16 + k4];
            acc[j].x = fmaf(xv.x, wa.x, acc[j].x); acc[j].y = fmaf(xv.x, wa.y, acc[j].y);
            acc[j].z = fmaf(xv.x, wa.z, acc[j].z); acc[j].w = fmaf(xv.x, wa.w, acc[j].w);
            acc[j].x = fmaf(xv.y, wb.x, acc[j].x); acc[j].y = fmaf(xv.y, wb.y, acc[j].y);
            acc[j].z = fmaf(xv.y, wb.z, acc[j].z); acc[j].w = fmaf(xv.y, wb.w, acc[j].w);
            acc[j].x = fmaf(xv.z, wc.x, acc[j].x); acc[j].y = fmaf(xv.z, wc.y, acc[j].y);
            acc[j].z = fmaf(xv.z, wc.z, acc[j].z); acc[j].w = fmaf(xv.z, wc.w, acc[j].w);
            acc[j].x = fmaf(xv.w, wd.x, acc[j].x); acc[j].y = fmaf(xv.w, wd.y, acc[j].y);
            acc[j].z = fmaf(xv.w, wd.z, acc[j].z); acc[j].w = fmaf(xv.w, wd.w, acc[j].w);
        }
    }
    const float4 b = *(const float4*)&bias[f0];
#pragma unroll
    for (int j = 0; j < 4; ++j) {
        int n = nbase + n0 + j;
        if (n >= N) continue;
        float4 a = acc[j];
        a.x = fmaxf(a.x + b.x, 0.f);
        a.y = fmaxf(a.y + b.y, 0.f);
        a.z = fmaxf(a.z + b.z, 0.f);
        a.w = fmaxf(a.w + b.w, 0.f);
        *(float4*)(out + (long long)n * 128 + f0) = a;
    }
}

// ---------------- Linear (layer 2): A2 = H1 @ W2 (bf16 out); 16 nodes / 128 thr ------

template <int K, bool RELU, bool OUTBF>
__global__ __launch_bounds__(128) void gnn_linear(const float* __restrict__ X,
                                                  const float* __restrict__ Wf,
                                                  const float* __restrict__ bias,
                                                  int N, void* __restrict__ out) {
    __shared__ float Xs[16 * K];
    const int t = threadIdx.x;
    const int nbase = blockIdx.x * 16;

#pragma unroll
    for (int it = 0; it < K / 32; ++it) {
        int i4 = t + it * 128;
        int n = nbase + (i4 * 4) / K;
        float4 v = make_float4(0.f, 0.f, 0.f, 0.f);
        if (n < N) v = ((const float4*)X)[(long long)nbase * (K / 4) + i4];
        ((float4*)Xs)[i4] = v;
    }
    __syncthreads();

    const int fg = t & 31, ng = t >> 5;
    const int f0 = fg * 4, n0 = ng * 4;
    const float4* Xs4 = (const float4*)Xs;            // [node][K/4]
    const float4* Wp  = (const float4*)Wf;            // [k][32]
    float4 acc[4];
#pragma unroll
    for (int j = 0; j < 4; ++j) acc[j] = make_float4(0.f, 0.f, 0.f, 0.f);
#pragma unroll 4
    for (int k4 = 0; k4 < K / 4; ++k4) {
        const float4 wa = Wp[(4 * k4 + 0) * 32 + fg];
        const float4 wb = Wp[(4 * k4 + 1) * 32 + fg];
        const float4 wc = Wp[(4 * k4 + 2) * 32 + fg];
        const float4 wd = Wp[(4 * k4 + 3) * 32 + fg];
#pragma unroll
        for (int j = 0; j < 4; ++j) {
            const float4 xv = Xs4[(n0 + j) * (K / 4) + k4];
            acc[j].x = fmaf(xv.x, wa.x, acc[j].x); acc[j].y = fmaf(xv.x, wa.y, acc[j].y);
            acc[j].z = fmaf(xv.x, wa.z, acc[j].z); acc[j].w = fmaf(xv.x, wa.w, acc[j].w);
            acc[j].x = fmaf(xv.y, wb.x, acc[j].x); acc[j].y = fmaf(xv.y, wb.y, acc[j].y);
            acc[j].z = fmaf(xv.y, wb.z, acc[j].z); acc[j].w = fmaf(xv.y, wb.w, acc[j].w);
            acc[j].x = fmaf(xv.z, wc.x, acc[j].x); acc[j].y = fmaf(xv.z, wc.y, acc[j].y);
            acc[j].z = fmaf(xv.z, wc.z, acc[j].z); acc[j].w = fmaf(xv.z, wc.w, acc[j].w);
            acc[j].x = fmaf(xv.w, wd.x, acc[j].x); acc[j].y = fmaf(xv.w, wd.y, acc[j].y);
            acc[j].z = fmaf(xv.w, wd.z, acc[j].z); acc[j].w = fmaf(xv.w, wd.w, acc[j].w);
        }
    }
#pragma unroll
    for (int j = 0; j < 4; ++j) {
        int n = nbase + n0 + j;
        if (n >= N) continue;
        float4 a = acc[j];
        if (RELU) {
            const float4 b = *(const float4*)&bias[f0];
            a.x = fmaxf(a.x + b.x, 0.f);
            a.y = fmaxf(a.y + b.y, 0.f);
            a.z = fmaxf(a.z + b.z, 0.f);
            a.w = fmaxf(a.w + b.w, 0.f);
        }
        if (OUTBF) {
            uint2 u;
            u.x = (unsigned int)f2bf(a.x) | ((unsigned int)f2bf(a.y) << 16);
            u.y = (unsigned int)f2bf(a.z) | ((unsigned int)f2bf(a.w) << 16);
            *(uint2*)((unsigned short*)out + (long long)n * 128 + f0) = u;
        } else {
            *(float4*)((float*)out + (long long)n * 128 + f0) = a;
        }
    }
}

// ---------------- Layer-2 aggregation over bf16 rows -> C2 (f32) ----------------
// 2 nodes/wave, lane covers 4 feats via uint2 (full 256B row per half-wave); 8-wide unroll.

template <bool SMALLN>
__global__ __launch_bounds__(256) void gnn_agg_bf(const unsigned short* __restrict__ A2,
                                                  const int* __restrict__ excl,
                                                  const int* __restrict__ bsums,
                                                  const void* __restrict__ csr,
                                                  const float* __restrict__ dis,
                                                  const float* __restrict__ bias,
                                                  float* __restrict__ outC, int N, int E) {
    int t = threadIdx.x;
    int lane = t & 63;
    int n = blockIdx.x * 8 + (t >> 6) * 2 + (lane >> 5);
    if (n >= N) return;
    int fl = lane & 31;                          // uint2 index within row
    float dn = dis[n];
    float dn2 = dn * dn;
    uint2 us = *(const uint2*)(A2 + (long long)n * 128 + fl * 4);
    float a0 = bfl(us.x) * dn2, a1 = bfh(us.x) * dn2;
    float a2 = bfl(us.y) * dn2, a3 = bfh(us.y) * dn2;
    int beg = excl[n] + bsums[n >> 8];
    int end = (n + 1 < N) ? (excl[n + 1] + bsums[(n + 1) >> 8]) : E;
    int e = beg;
    for (; e + 8 <= end; e += 8) {
        int s0 = csr_at<SMALLN>(csr, e),     s1 = csr_at<SMALLN>(csr, e + 1);
        int s2 = csr_at<SMALLN>(csr, e + 2), s3 = csr_at<SMALLN>(csr, e + 3);
        int s4 = csr_at<SMALLN>(csr, e + 4), s5 = csr_at<SMALLN>(csr, e + 5);
        int s6 = csr_at<SMALLN>(csr, e + 6), s7 = csr_at<SMALLN>(csr, e + 7);
        float w0 = dis[s0], w1 = dis[s1], w2 = dis[s2], w3 = dis[s3];
        float w4 = dis[s4], w5 = dis[s5], w6 = dis[s6], w7 = dis[s7];
        uint2 u0 = *(const uint2*)(A2 + (long long)s0 * 128 + fl * 4);
        uint2 u1 = *(const uint2*)(A2 + (long long)s1 * 128 + fl * 4);
        uint2 u2 = *(const uint2*)(A2 + (long long)s2 * 128 + fl * 4);
        uint2 u3 = *(const uint2*)(A2 + (long long)s3 * 128 + fl * 4);
        uint2 u4 = *(const uint2*)(A2 + (long long)s4 * 128 + fl * 4);
        uint2 u5 = *(const uint2*)(A2 + (long long)s5 * 128 + fl * 4);
        uint2 u6 = *(const uint2*)(A2 + (long long)s6 * 128 + fl * 4);
        uint2 u7 = *(const uint2*)(A2 + (long long)s7 * 128 + fl * 4);
        w0 *= dn; w1 *= dn; w2 *= dn; w3 *= dn;
        w4 *= dn; w5 *= dn; w6 *= dn; w7 *= dn;
        a0 = fmaf(w0, bfl(u0.x), a0); a1 = fmaf(w0, bfh(u0.x), a1);
        a2 = fmaf(w0, bfl(u0.y), a2); a3 = fmaf(w0, bfh(u0.y), a3);
        a0 = fmaf(w1, bfl(u1.x), a0); a1 = fmaf(w1, bfh(u1.x), a1);
        a2 = fmaf(w1, bfl(u1.y), a2); a3 = fmaf(w1, bfh(u1.y), a3);
        a0 = fmaf(w2, bfl(u2.x), a0); a1 = fmaf(w2, bfh(u2.x), a1);
        a2 = fmaf(w2, bfl(u2.y), a2); a3 = fmaf(w2, bfh(u2.y), a3);
        a0 = fmaf(w3, bfl(u3.x), a0); a1 = fmaf(w3, bfh(u3.x), a1);
        a2 = fmaf(w3, bfl(u3.y), a2); a3 = fmaf(w3, bfh(u3.y), a3);
        a0 = fmaf(w4, bfl(u4.x), a0); a1 = fmaf(w4, bfh(u4.x), a1);
        a2 = fmaf(w4, bfl(u4.y), a2); a3 = fmaf(w4, bfh(u4.y), a3);
        a0 = fmaf(w5, bfl(u5.x), a0); a1 = fmaf(w5, bfh(u5.x), a1);
        a2 = fmaf(w5, bfl(u5.y), a2); a3 = fmaf(w5, bfh(u5.y), a3);
        a0 = fmaf(w6, bfl(u6.x), a0); a1 = fmaf(w6, bfh(u6.x), a1);
        a2 = fmaf(w6, bfl(u6.y), a2); a3 = fmaf(w6, bfh(u6.y), a3);
        a0 = fmaf(w7, bfl(u7.x), a0); a1 = fmaf(w7, bfh(u7.x), a1);
        a2 = fmaf(w7, bfl(u7.y), a2); a3 = fmaf(w7, bfh(u7.y), a3);
    }
    for (; e + 4 <= end; e += 4) {
        int s0 = csr_at<SMALLN>(csr, e),     s1 = csr_at<SMALLN>(csr, e + 1);
        int s2 = csr_at<SMALLN>(csr, e + 2), s3 = csr_at<SMALLN>(csr, e + 3);
        float w0 = dis[s0], w1 = dis[s1], w2 = dis[s2], w3 = dis[s3];
        uint2 u0 = *(const uint2*)(A2 + (long long)s0 * 128 + fl * 4);
        uint2 u1 = *(const uint2*)(A2 + (long long)s1 * 128 + fl * 4);
        uint2 u2 = *(const uint2*)(A2 + (long long)s2 * 128 + fl * 4);
        uint2 u3 = *(const uint2*)(A2 + (long long)s3 * 128 + fl * 4);
        w0 *= dn; w1 *= dn; w2 *= dn; w3 *= dn;
        a0 = fmaf(w0, bfl(u0.x), a0); a1 = fmaf(w0, bfh(u0.x), a1);
        a2 = fmaf(w0, bfl(u0.y), a2); a3 = fmaf(w0, bfh(u0.y), a3);
        a0 = fmaf(w1, bfl(u1.x), a0); a1 = fmaf(w1, bfh(u1.x), a1);
        a2 = fmaf(w1, bfl(u1.y), a2); a3 = fmaf(w1, bfh(u1.y), a3);
        a0 = fmaf(w2, bfl(u2.x), a0); a1 = fmaf(w2, bfh(u2.x), a1);
        a2 = fmaf(w2, bfl(u2.y), a2); a3 = fmaf(w2, bfh(u2.y), a3);
        a0 = fmaf(w3, bfl(u3.x), a0); a1 = fmaf(w3, bfh(u3.x), a1);
        a2 = fmaf(w3, bfl(u3.y), a2); a3 = fmaf(w3, bfh(u3.y), a3);
    }
    for (; e < end; ++e) {
        int s = csr_at<SMALLN>(csr, e);
        float w = dis[s] * dn;
        uint2 u = *(const uint2*)(A2 + (long long)s * 128 + fl * 4);
        a0 = fmaf(w, bfl(u.x), a0); a1 = fmaf(w, bfh(u.x), a1);
        a2 = fmaf(w, bfl(u.y), a2); a3 = fmaf(w, bfh(u.y), a3);
    }
    const float4 b = *(const float4*)&bias[fl * 4];
    float4 o;
    o.x = fmaxf(a0 + b.x, 0.f);
    o.y = fmaxf(a1 + b.y, 0.f);
    o.z = fmaxf(a2 + b.z, 0.f);
    o.w = fmaxf(a3 + b.w, 0.f);
    *(float4*)(outC + (long long)n * 128 + fl * 4) = o;
}

// ---------------- Pool (batch sorted): 32-node strips, pre-reduced atomic flush -------

#define PSTRIP 32
__global__ __launch_bounds__(128) void gnn_pool(const float* __restrict__ h,
                                                const int* __restrict__ batch,
                                                const int* __restrict__ flags,
                                                float* __restrict__ pooled, int N, int B) {
    int i64 = flags[1];
    int f = threadIdx.x;
    int n0 = blockIdx.x * PSTRIP;
    if (n0 >= N) return;
    int nend = min(n0 + PSTRIP, N);
    int cur = clampi(ld_idx(batch, n0, i64), 0, B - 1);
    float acc = 0.0f;
    for (int n = n0; n < nend; ++n) {
        int b = clampi(ld_idx(batch, n, i64), 0, B - 1);
        if (b != cur) {
            atomicAdd(&pooled[cur * 128 + f], acc);
            acc = 0.0f; cur = b;
        }
        acc += h[(long long)n * 128 + f];
    }
    atomicAdd(&pooled[cur * 128 + f], acc);
}

// ---------------- head: mean (cnt via binary search) + MLP ----------------

__global__ __launch_bounds__(128) void gnn_head(const float* __restrict__ pooled,
                                                const int* __restrict__ batch,
                                                const float* __restrict__ W3,
                                                const float* __restrict__ b3,
                                                const float* __restrict__ W4,
                                                const float* __restrict__ b4,
                                                const int* __restrict__ flags,
                                                void* __restrict__ outv, int N) {
    __shared__ float xs[128];
    __shared__ float rs[128];
    __shared__ float cinv;
    int b = blockIdx.x, f = threadIdx.x;
    if (f == 0) {
        int i64 = flags[1];
        int L = 0, R = N;
        while (L < R) { int m = (L + R) >> 1; if (ld_idx(batch, m, i64) < b) L = m + 1; else R = m; }
        int lo = L;
        L = 0; R = N;
        while (L < R) { int m = (L + R) >> 1; if (ld_idx(batch, m, i64) < b + 1) L = m + 1; else R = m; }
        cinv = 1.0f / fmaxf((float)(L - lo), 1.0f);
    }
    __syncthreads();
    xs[f] = pooled[b * 128 + f] * cinv;
    __syncthreads();
    float acc = b3[f];
    for (int k = 0; k < 128; ++k) acc = fmaf(xs[k], W3[k * 128 + f], acc);
    rs[f] = fmaxf(acc, 0.f);
    __syncthreads();
    if (f < 64) {
        float a2 = b4[f];
        for (int k = 0; k < 128; ++k) a2 = fmaf(rs[k], W4[k * 64 + f], a2);
        if (flags[0]) ((float*)outv)[b * 64 + f] = a2;
        else          ((unsigned short*)outv)[b * 64 + f] = f2bf(a2);
    }
}

// ---------------- Launch ----------------

extern "C" void kernel_launch(void* const* d_in, const int* in_sizes, int n_in,
                              void* d_out, int out_size, void* d_ws, size_t ws_size,
                              hipStream_t stream) {
    const void* x  = d_in[0];
    const int* ei  = (const int*)d_in[1];
    const int* bat = (const int*)d_in[2];

    const int N = in_sizes[0] / 64;    // 50000
    const int E = in_sizes[1] / 2;     // 800000
    const int B = out_size / 64;       // 64
    const bool smalln = (N < 65536);

    char* p = (char*)d_ws;
    auto alloc = [&](size_t bytes) { void* q = (void*)p; p += (bytes + 255) & ~(size_t)255; return q; };
    int*   flags    = (int*)alloc(256);
    float* wsW      = (float*)alloc((size_t)OTOT * 4);
    int*   degcnt   = (int*)alloc((size_t)N * 4);
    float* dis      = (float*)alloc((size_t)N * 4);
    int*   excl     = (int*)alloc((size_t)N * 4);
    int*   sums     = (int*)alloc(1024);
    int*   bsums    = (int*)alloc(1024);
    int*   rank     = (int*)alloc((size_t)E * 4);
    void*  csr      = alloc((size_t)E * (smalln ? 2 : 4));
    unsigned short* xb = (unsigned short*)alloc((size_t)N * 64 * 2);
    float* H1       = (float*)alloc((size_t)N * 128 * 4);
    float* C2       = (float*)alloc((size_t)N * 128 * 4);
    unsigned short* A2 = (unsigned short*)alloc((size_t)N * 128 * 2);
    float* pooled   = (float*)alloc((size_t)B * 128 * 4);
    (void)ws_size; (void)n_in;

    const int nbN = (N + 255) / 256;   // 196 (<=256 for last-block scan)

    gnn_prep<<<512, 256, 0, stream>>>(d_in[3], d_in[4], d_in[5], d_in[6],
                                      d_in[7], d_in[8], d_in[9], d_in[10],
                                      x, ei, flags, degcnt, pooled, wsW, xb, N, B);

    gnn_hist<<<(E + 1023) / 1024, 256, 0, stream>>>(ei, E, N, flags, degcnt, rank);
    gnn_scan1<<<nbN, 256, 0, stream>>>(degcnt, excl, sums, bsums, dis, flags + 8, N, nbN);
    if (smalln)
        gnn_fill<true><<<(E + 1023) / 1024, 256, 0, stream>>>(ei, excl, bsums, rank, csr, E, N, flags);
    else
        gnn_fill<false><<<(E + 1023) / 1024, 256, 0, stream>>>(ei, excl, bsums, rank, csr, E, N, flags);

    const int nlin = (N + 15) / 16;    // 16-node blocks, 128 threads
    const int nagg = (N + 7) / 8;

    // layer 1 (fused): H1 = relu((A_hat @ x) @ W1 + b1)
    if (smalln)
        gnn_aggx_lin1<true><<<nlin, 128, 0, stream>>>(x, xb, excl, bsums, csr, dis, flags,
                                                      wsW + OW1, wsW + OB1, N, E, H1);
    else
        gnn_aggx_lin1<false><<<nlin, 128, 0, stream>>>(x, xb, excl, bsums, csr, dis, flags,
                                                       wsW + OW1, wsW + OB1, N, E, H1);

    // layer 2: A2 = H1 @ W2 (bf16) ; C2 = relu(A_hat @ A2 + b2)
    gnn_linear<128, false, true><<<nlin, 128, 0, stream>>>(H1, wsW + OW2, wsW + OB2, N, (void*)A2);
    if (smalln)
        gnn_agg_bf<true><<<nagg, 256, 0, stream>>>(A2, excl, bsums, csr, dis, wsW + OB2, C2, N, E);
    else
        gnn_agg_bf<false><<<nagg, 256, 0, stream>>>(A2, excl, bsums, csr, dis, wsW + OB2, C2, N, E);

    // pool + head
    gnn_pool<<<(N + PSTRIP - 1) / PSTRIP, 128, 0, stream>>>(C2, bat, flags, pooled, N, B);
    gnn_head<<<B, 128, 0, stream>>>(pooled, bat, wsW + OW3, wsW + OB3,
                                    wsW + OW4, wsW + OB4, flags, d_out, N);
}

// Round 15
// 272.126 us; speedup vs baseline: 1.1242x; 1.0635x over previous
//
#include <hip/hip_runtime.h>

// ---------------- helpers ----------------

__device__ __forceinline__ float ldf(const void* p, long long i, int f32) {
    if (f32) return ((const float*)p)[i];
    unsigned int u = ((const unsigned short*)p)[i];
    return __uint_as_float(u << 16);
}
__device__ __forceinline__ float bfl(unsigned int u) { return __uint_as_float(u << 16); }
__device__ __forceinline__ float bfh(unsigned int u) { return __uint_as_float(u & 0xFFFF0000u); }
__device__ __forceinline__ int ld_idx(const int* p, long long i, int i64) {
    return i64 ? p[2 * i] : p[i];   // little-endian low word of int64
}
__device__ __forceinline__ unsigned short f2bf(float v) {
    unsigned int x = __float_as_uint(v);
    return (unsigned short)((x + 0x7FFFu + ((x >> 16) & 1u)) >> 16);  // RNE
}
__device__ __forceinline__ int clampi(int v, int lo, int hi) {
    return v < lo ? lo : (v > hi ? hi : v);
}

// ---------------- weights layout (contiguous f32) ----------------
#define OW1 0
#define OB1 8192
#define OW2 8320
#define OB2 24704
#define OW3 24832
#define OB3 41216
#define OW4 41344
#define OB4 49536
#define OTOT 49600

// ---------------- prep: dtype-detect + zero-init + weight/x convert ----------------
// flags[0]=1 f32 floats / 0 bf16 ; flags[1]=1 int64 / 0 int32

__global__ void gnn_prep(const void* W1, const void* b1, const void* W2, const void* b2,
                         const void* W3, const void* b3, const void* W4, const void* b4,
                         const void* x, const int* __restrict__ ei,
                         int* __restrict__ flags_out,
                         int* __restrict__ degcnt, float* __restrict__ pooled,
                         float* __restrict__ wsW, unsigned short* __restrict__ xb,
                         int N, int B) {
    __shared__ int s_cnt, s_or;
    const int t = threadIdx.x;
    if (t == 0) { s_cnt = 0; s_or = 0; }
    __syncthreads();
    {
        const unsigned int* w1w = (const unsigned int*)W1;
        int c = 0, o = 0;
        for (int i = t; i < 512; i += 256) {
            unsigned int e = (w1w[i] >> 7) & 0xFFu;
            if (e >= 100 && e <= 140) c++;
        }
        for (int i = t; i < 1024; i += 256) o |= ei[2 * i + 1];
        atomicAdd(&s_cnt, c);
        atomicOr(&s_or, o);
    }
    __syncthreads();
    const int f32 = (s_cnt > 256) ? 0 : 1;
    if (blockIdx.x == 0 && t == 0) {
        flags_out[0] = f32;
        flags_out[1] = (s_or == 0) ? 1 : 0;
    }
    const int i = blockIdx.x * 256 + t;
    const int stride = gridDim.x * 256;
    for (int j = i; j < N; j += stride) degcnt[j] = 0;
    for (int j = i; j < B * 128; j += stride) pooled[j] = 0.f;
    for (int j = i; j < OTOT; j += stride) {
        float v;
        if      (j < OB1) v = ldf(W1, j - OW1, f32);
        else if (j < OW2) v = ldf(b1, j - OB1, f32);
        else if (j < OB2) v = ldf(W2, j - OW2, f32);
        else if (j < OW3) v = ldf(b2, j - OB2, f32);
        else if (j < OB3) v = ldf(W3, j - OW3, f32);
        else if (j < OW4) v = ldf(b3, j - OB3, f32);
        else if (j < OB4) v = ldf(W4, j - OW4, f32);
        else              v = ldf(b4, j - OB4, f32);
        wsW[j] = v;
    }
    if (f32) {
        const float* xf = (const float*)x;
        for (int j = i; j < N * 64; j += stride) xb[j] = f2bf(xf[j]);
    }
}

// ---------------- CSR build ----------------

__global__ void gnn_hist(const int* __restrict__ ei, int E, int N,
                         const int* __restrict__ flags, int* __restrict__ degcnt,
                         int* __restrict__ rank) {
    int base = (blockIdx.x * 256 + threadIdx.x) * 4;
    if (base >= E) return;
    int i64 = flags[1];
    int m = min(4, E - base);
    int d[4], r[4];
#pragma unroll
    for (int j = 0; j < 4; ++j)
        if (j < m) d[j] = clampi(ld_idx(ei, (long long)E + base + j, i64), 0, N - 1);
#pragma unroll
    for (int j = 0; j < 4; ++j)
        if (j < m) r[j] = atomicAdd(&degcnt[d[j]], 1);
#pragma unroll
    for (int j = 0; j < 4; ++j)
        if (j < m) rank[base + j] = r[j];
}

__global__ void gnn_scan1(const int* __restrict__ cnt, int* __restrict__ excl,
                          int* __restrict__ sums, float* __restrict__ dis, int N) {
    __shared__ int sh[256];
    int t = threadIdx.x;
    int i = blockIdx.x * 256 + t;
    int v = (i < N) ? cnt[i] : 0;
    sh[t] = v;
    __syncthreads();
    for (int off = 1; off < 256; off <<= 1) {
        int a = (t >= off) ? sh[t - off] : 0;
        __syncthreads();
        sh[t] += a;
        __syncthreads();
    }
    if (i < N) {
        excl[i] = sh[t] - v;
        dis[i] = rsqrtf((float)v + 1.0f);
    }
    if (t == 255) sums[blockIdx.x] = sh[255];
}

__global__ void gnn_scan2(int* __restrict__ sums, int nb) {
    __shared__ int sh[256];
    int t = threadIdx.x;
    int v = (t < nb) ? sums[t] : 0;
    sh[t] = v;
    __syncthreads();
    for (int off = 1; off < 256; off <<= 1) {
        int a = (t >= off) ? sh[t - off] : 0;
        __syncthreads();
        sh[t] += a;
        __syncthreads();
    }
    if (t < nb) sums[t] = sh[t] - v;
}

template <bool SMALLN>
__global__ void gnn_fill(const int* __restrict__ ei, const int* __restrict__ excl,
                         const int* __restrict__ bsums, const int* __restrict__ rank,
                         void* __restrict__ csr, int E, int N,
                         const int* __restrict__ flags) {
    int e = blockIdx.x * 256 + threadIdx.x;
    if (e >= E) return;
    int i64 = flags[1];
    int s = clampi(ld_idx(ei, (long long)e, i64), 0, N - 1);
    int d = clampi(ld_idx(ei, (long long)E + e, i64), 0, N - 1);
    int pos = excl[d] + bsums[d >> 8] + rank[e];
    if (SMALLN) ((unsigned short*)csr)[pos] = (unsigned short)s;
    else        ((int*)csr)[pos] = s;
}

template <bool SMALLN>
__device__ __forceinline__ int csr_at(const void* csr, int e) {
    return SMALLN ? (int)((const unsigned short*)csr)[e] : ((const int*)csr)[e];
}

// ---------------- fused layer 1: aggX (LDS) then X@W1+b1 -> relu -> H1 ----------------
// 16 nodes/block, 128 threads. Phase A: 4 passes x (2 nodes/wave x 2 waves),
// 8-wide edge unroll. Phase B: K=64 GEMM, W from L2.

template <bool SMALLN>
__global__ __launch_bounds__(128) void gnn_aggx_lin1(const void* __restrict__ x,
                                                     const unsigned short* __restrict__ xconv,
                                                     const int* __restrict__ excl,
                                                     const int* __restrict__ bsums,
                                                     const void* __restrict__ csr,
                                                     const float* __restrict__ dis,
                                                     const int* __restrict__ flags,
                                                     const float* __restrict__ Wf,
                                                     const float* __restrict__ bias,
                                                     int N, int E, float* __restrict__ out) {
    __shared__ float Xs[16 * 64];   // 4 KB
    const unsigned int* tab = flags[0] ? (const unsigned int*)xconv : (const unsigned int*)x;
    const int t = threadIdx.x;
    const int nbase = blockIdx.x * 16;
    const int lane = t & 63;
    const int fl = lane & 31;

#pragma unroll
    for (int pass = 0; pass < 4; ++pass) {
        int ln = pass * 4 + (t >> 6) * 2 + (lane >> 5);
        int n = nbase + ln;
        float a0 = 0.f, a1 = 0.f;
        if (n < N) {
            float dn = dis[n], dn2 = dn * dn;
            unsigned int us = tab[(long long)n * 32 + fl];
            a0 = bfl(us) * dn2; a1 = bfh(us) * dn2;
            int beg = excl[n] + bsums[n >> 8];
            int end = (n + 1 < N) ? (excl[n + 1] + bsums[(n + 1) >> 8]) : E;
            int e = beg;
            for (; e + 8 <= end; e += 8) {
                int s0 = csr_at<SMALLN>(csr, e),     s1 = csr_at<SMALLN>(csr, e + 1);
                int s2 = csr_at<SMALLN>(csr, e + 2), s3 = csr_at<SMALLN>(csr, e + 3);
                int s4 = csr_at<SMALLN>(csr, e + 4), s5 = csr_at<SMALLN>(csr, e + 5);
                int s6 = csr_at<SMALLN>(csr, e + 6), s7 = csr_at<SMALLN>(csr, e + 7);
                float w0 = dis[s0], w1 = dis[s1], w2 = dis[s2], w3 = dis[s3];
                float w4 = dis[s4], w5 = dis[s5], w6 = dis[s6], w7 = dis[s7];
                unsigned int u0 = tab[(long long)s0 * 32 + fl];
                unsigned int u1 = tab[(long long)s1 * 32 + fl];
                unsigned int u2 = tab[(long long)s2 * 32 + fl];
                unsigned int u3 = tab[(long long)s3 * 32 + fl];
                unsigned int u4 = tab[(long long)s4 * 32 + fl];
                unsigned int u5 = tab[(long long)s5 * 32 + fl];
                unsigned int u6 = tab[(long long)s6 * 32 + fl];
                unsigned int u7 = tab[(long long)s7 * 32 + fl];
                w0 *= dn; w1 *= dn; w2 *= dn; w3 *= dn;
                w4 *= dn; w5 *= dn; w6 *= dn; w7 *= dn;
                a0 = fmaf(w0, bfl(u0), a0); a1 = fmaf(w0, bfh(u0), a1);
                a0 = fmaf(w1, bfl(u1), a0); a1 = fmaf(w1, bfh(u1), a1);
                a0 = fmaf(w2, bfl(u2), a0); a1 = fmaf(w2, bfh(u2), a1);
                a0 = fmaf(w3, bfl(u3), a0); a1 = fmaf(w3, bfh(u3), a1);
                a0 = fmaf(w4, bfl(u4), a0); a1 = fmaf(w4, bfh(u4), a1);
                a0 = fmaf(w5, bfl(u5), a0); a1 = fmaf(w5, bfh(u5), a1);
                a0 = fmaf(w6, bfl(u6), a0); a1 = fmaf(w6, bfh(u6), a1);
                a0 = fmaf(w7, bfl(u7), a0); a1 = fmaf(w7, bfh(u7), a1);
            }
            for (; e + 4 <= end; e += 4) {
                int s0 = csr_at<SMALLN>(csr, e),     s1 = csr_at<SMALLN>(csr, e + 1);
                int s2 = csr_at<SMALLN>(csr, e + 2), s3 = csr_at<SMALLN>(csr, e + 3);
                float w0 = dis[s0], w1 = dis[s1], w2 = dis[s2], w3 = dis[s3];
                unsigned int u0 = tab[(long long)s0 * 32 + fl];
                unsigned int u1 = tab[(long long)s1 * 32 + fl];
                unsigned int u2 = tab[(long long)s2 * 32 + fl];
                unsigned int u3 = tab[(long long)s3 * 32 + fl];
                w0 *= dn; w1 *= dn; w2 *= dn; w3 *= dn;
                a0 = fmaf(w0, bfl(u0), a0); a1 = fmaf(w0, bfh(u0), a1);
                a0 = fmaf(w1, bfl(u1), a0); a1 = fmaf(w1, bfh(u1), a1);
                a0 = fmaf(w2, bfl(u2), a0); a1 = fmaf(w2, bfh(u2), a1);
                a0 = fmaf(w3, bfl(u3), a0); a1 = fmaf(w3, bfh(u3), a1);
            }
            for (; e < end; ++e) {
                int s = csr_at<SMALLN>(csr, e);
                float w = dis[s] * dn;
                unsigned int u = tab[(long long)s * 32 + fl];
                a0 = fmaf(w, bfl(u), a0); a1 = fmaf(w, bfh(u), a1);
            }
        }
        Xs[ln * 64 + fl * 2]     = a0;
        Xs[ln * 64 + fl * 2 + 1] = a1;
    }
    __syncthreads();

    const int fg = t & 31, ng = t >> 5;          // ng 0..3 -> nodes ng*4..ng*4+3
    const int f0 = fg * 4, n0 = ng * 4;
    const float4* Xs4 = (const float4*)Xs;       // [node][16]
    const float4* Wp  = (const float4*)Wf;       // [k][32]
    float4 acc[4];
#pragma unroll
    for (int j = 0; j < 4; ++j) acc[j] = make_float4(0.f, 0.f, 0.f, 0.f);
#pragma unroll 4
    for (int k4 = 0; k4 < 16; ++k4) {
        const float4 wa = Wp[(4 * k4 + 0) * 32 + fg];
        const float4 wb = Wp[(4 * k4 + 1) * 32 + fg];
        const float4 wc = Wp[(4 * k4 + 2) * 32 + fg];
        const float4 wd = Wp[(4 * k4 + 3) * 32 + fg];
#pragma unroll
        for (int j = 0; j < 4; ++j) {
            const float4 xv = Xs4[(n0 + j) * 16 + k4];
            acc[j].x = fmaf(xv.x, wa.x, acc[j].x); acc[j].y = fmaf(xv.x, wa.y, acc[j].y);
            acc[j].z = fmaf(xv.x, wa.z, acc[j].z); acc[j].w = fmaf(xv.x, wa.w, acc[j].w);
            acc[j].x = fmaf(xv.y, wb.x, acc[j].x); acc[j].y = fmaf(xv.y, wb.y, acc[j].y);
            acc[j].z = fmaf(xv.y, wb.z, acc[j].z); acc[j].w = fmaf(xv.y, wb.w, acc[j].w);
            acc[j].x = fmaf(xv.z, wc.x, acc[j].x); acc[j].y = fmaf(xv.z, wc.y, acc[j].y);
            acc[j].z = fmaf(xv.z, wc.z, acc[j].z); acc[j].w = fmaf(xv.z, wc.w, acc[j].w);
            acc[j].x = fmaf(xv.w, wd.x, acc[j].x); acc[j].y = fmaf(xv.w, wd.y, acc[j].y);
            acc[j].z = fmaf(xv.w, wd.z, acc[j].z); acc[j].w = fmaf(xv.w, wd.w, acc[j].w);
        }
    }
    const float4 b = *(const float4*)&bias[f0];
#pragma unroll
    for (int j = 0; j < 4; ++j) {
        int n = nbase + n0 + j;
        if (n >= N) continue;
        float4 a = acc[j];
        a.x = fmaxf(a.x + b.x, 0.f);
        a.y = fmaxf(a.y + b.y, 0.f);
        a.z = fmaxf(a.z + b.z, 0.f);
        a.w = fmaxf(a.w + b.w, 0.f);
        *(float4*)(out + (long long)n * 128 + f0) = a;
    }
}

// ---------------- Linear (layer 2): A2 = H1 @ W2 (bf16 out); 16 nodes / 128 thr ------

template <int K, bool RELU, bool OUTBF>
__global__ __launch_bounds__(128) void gnn_linear(const float* __restrict__ X,
                                                  const float* __restrict__ Wf,
                                                  const float* __restrict__ bias,
                                                  int N, void* __restrict__ out) {
    __shared__ float Xs[16 * K];
    const int t = threadIdx.x;
    const int nbase = blockIdx.x * 16;

#pragma unroll
    for (int it = 0; it < K / 32; ++it) {
        int i4 = t + it * 128;
        int n = nbase + (i4 * 4) / K;
        float4 v = make_float4(0.f, 0.f, 0.f, 0.f);
        if (n < N) v = ((const float4*)X)[(long long)nbase * (K / 4) + i4];
        ((float4*)Xs)[i4] = v;
    }
    __syncthreads();

    const int fg = t & 31, ng = t >> 5;
    const int f0 = fg * 4, n0 = ng * 4;
    const float4* Xs4 = (const float4*)Xs;            // [node][K/4]
    const float4* Wp  = (const float4*)Wf;            // [k][32]
    float4 acc[4];
#pragma unroll
    for (int j = 0; j < 4; ++j) acc[j] = make_float4(0.f, 0.f, 0.f, 0.f);
#pragma unroll 4
    for (int k4 = 0; k4 < K / 4; ++k4) {
        const float4 wa = Wp[(4 * k4 + 0) * 32 + fg];
        const float4 wb = Wp[(4 * k4 + 1) * 32 + fg];
        const float4 wc = Wp[(4 * k4 + 2) * 32 + fg];
        const float4 wd = Wp[(4 * k4 + 3) * 32 + fg];
#pragma unroll
        for (int j = 0; j < 4; ++j) {
            const float4 xv = Xs4[(n0 + j) * (K / 4) + k4];
            acc[j].x = fmaf(xv.x, wa.x, acc[j].x); acc[j].y = fmaf(xv.x, wa.y, acc[j].y);
            acc[j].z = fmaf(xv.x, wa.z, acc[j].z); acc[j].w = fmaf(xv.x, wa.w, acc[j].w);
            acc[j].x = fmaf(xv.y, wb.x, acc[j].x); acc[j].y = fmaf(xv.y, wb.y, acc[j].y);
            acc[j].z = fmaf(xv.y, wb.z, acc[j].z); acc[j].w = fmaf(xv.y, wb.w, acc[j].w);
            acc[j].x = fmaf(xv.z, wc.x, acc[j].x); acc[j].y = fmaf(xv.z, wc.y, acc[j].y);
            acc[j].z = fmaf(xv.z, wc.z, acc[j].z); acc[j].w = fmaf(xv.z, wc.w, acc[j].w);
            acc[j].x = fmaf(xv.w, wd.x, acc[j].x); acc[j].y = fmaf(xv.w, wd.y, acc[j].y);
            acc[j].z = fmaf(xv.w, wd.z, acc[j].z); acc[j].w = fmaf(xv.w, wd.w, acc[j].w);
        }
    }
#pragma unroll
    for (int j = 0; j < 4; ++j) {
        int n = nbase + n0 + j;
        if (n >= N) continue;
        float4 a = acc[j];
        if (RELU) {
            const float4 b = *(const float4*)&bias[f0];
            a.x = fmaxf(a.x + b.x, 0.f);
            a.y = fmaxf(a.y + b.y, 0.f);
            a.z = fmaxf(a.z + b.z, 0.f);
            a.w = fmaxf(a.w + b.w, 0.f);
        }
        if (OUTBF) {
            uint2 u;
            u.x = (unsigned int)f2bf(a.x) | ((unsigned int)f2bf(a.y) << 16);
            u.y = (unsigned int)f2bf(a.z) | ((unsigned int)f2bf(a.w) << 16);
            *(uint2*)((unsigned short*)out + (long long)n * 128 + f0) = u;
        } else {
            *(float4*)((float*)out + (long long)n * 128 + f0) = a;
        }
    }
}

// ---------------- Layer-2 aggregation over bf16 rows -> C2 (f32) ----------------

template <bool SMALLN>
__global__ __launch_bounds__(256) void gnn_agg_bf(const unsigned short* __restrict__ A2,
                                                  const int* __restrict__ excl,
                                                  const int* __restrict__ bsums,
                                                  const void* __restrict__ csr,
                                                  const float* __restrict__ dis,
                                                  const float* __restrict__ bias,
                                                  float* __restrict__ outC, int N, int E) {
    int t = threadIdx.x;
    int lane = t & 63;
    int n = blockIdx.x * 8 + (t >> 6) * 2 + (lane >> 5);
    if (n >= N) return;
    int fl = lane & 31;                          // uint2 index within row
    float dn = dis[n];
    float dn2 = dn * dn;
    uint2 us = *(const uint2*)(A2 + (long long)n * 128 + fl * 4);
    float a0 = bfl(us.x) * dn2, a1 = bfh(us.x) * dn2;
    float a2 = bfl(us.y) * dn2, a3 = bfh(us.y) * dn2;
    int beg = excl[n] + bsums[n >> 8];
    int end = (n + 1 < N) ? (excl[n + 1] + bsums[(n + 1) >> 8]) : E;
    int e = beg;
    for (; e + 8 <= end; e += 8) {
        int s0 = csr_at<SMALLN>(csr, e),     s1 = csr_at<SMALLN>(csr, e + 1);
        int s2 = csr_at<SMALLN>(csr, e + 2), s3 = csr_at<SMALLN>(csr, e + 3);
        int s4 = csr_at<SMALLN>(csr, e + 4), s5 = csr_at<SMALLN>(csr, e + 5);
        int s6 = csr_at<SMALLN>(csr, e + 6), s7 = csr_at<SMALLN>(csr, e + 7);
        float w0 = dis[s0], w1 = dis[s1], w2 = dis[s2], w3 = dis[s3];
        float w4 = dis[s4], w5 = dis[s5], w6 = dis[s6], w7 = dis[s7];
        uint2 u0 = *(const uint2*)(A2 + (long long)s0 * 128 + fl * 4);
        uint2 u1 = *(const uint2*)(A2 + (long long)s1 * 128 + fl * 4);
        uint2 u2 = *(const uint2*)(A2 + (long long)s2 * 128 + fl * 4);
        uint2 u3 = *(const uint2*)(A2 + (long long)s3 * 128 + fl * 4);
        uint2 u4 = *(const uint2*)(A2 + (long long)s4 * 128 + fl * 4);
        uint2 u5 = *(const uint2*)(A2 + (long long)s5 * 128 + fl * 4);
        uint2 u6 = *(const uint2*)(A2 + (long long)s6 * 128 + fl * 4);
        uint2 u7 = *(const uint2*)(A2 + (long long)s7 * 128 + fl * 4);
        w0 *= dn; w1 *= dn; w2 *= dn; w3 *= dn;
        w4 *= dn; w5 *= dn; w6 *= dn; w7 *= dn;
        a0 = fmaf(w0, bfl(u0.x), a0); a1 = fmaf(w0, bfh(u0.x), a1);
        a2 = fmaf(w0, bfl(u0.y), a2); a3 = fmaf(w0, bfh(u0.y), a3);
        a0 = fmaf(w1, bfl(u1.x), a0); a1 = fmaf(w1, bfh(u1.x), a1);
        a2 = fmaf(w1, bfl(u1.y), a2); a3 = fmaf(w1, bfh(u1.y), a3);
        a0 = fmaf(w2, bfl(u2.x), a0); a1 = fmaf(w2, bfh(u2.x), a1);
        a2 = fmaf(w2, bfl(u2.y), a2); a3 = fmaf(w2, bfh(u2.y), a3);
        a0 = fmaf(w3, bfl(u3.x), a0); a1 = fmaf(w3, bfh(u3.x), a1);
        a2 = fmaf(w3, bfl(u3.y), a2); a3 = fmaf(w3, bfh(u3.y), a3);
        a0 = fmaf(w4, bfl(u4.x), a0); a1 = fmaf(w4, bfh(u4.x), a1);
        a2 = fmaf(w4, bfl(u4.y), a2); a3 = fmaf(w4, bfh(u4.y), a3);
        a0 = fmaf(w5, bfl(u5.x), a0); a1 = fmaf(w5, bfh(u5.x), a1);
        a2 = fmaf(w5, bfl(u5.y), a2); a3 = fmaf(w5, bfh(u5.y), a3);
        a0 = fmaf(w6, bfl(u6.x), a0); a1 = fmaf(w6, bfh(u6.x), a1);
        a2 = fmaf(w6, bfl(u6.y), a2); a3 = fmaf(w6, bfh(u6.y), a3);
        a0 = fmaf(w7, bfl(u7.x), a0); a1 = fmaf(w7, bfh(u7.x), a1);
        a2 = fmaf(w7, bfl(u7.y), a2); a3 = fmaf(w7, bfh(u7.y), a3);
    }
    for (; e + 4 <= end; e += 4) {
        int s0 = csr_at<SMALLN>(csr, e),     s1 = csr_at<SMALLN>(csr, e + 1);
        int s2 = csr_at<SMALLN>(csr, e + 2), s3 = csr_at<SMALLN>(csr, e + 3);
        float w0 = dis[s0], w1 = dis[s1], w2 = dis[s2], w3 = dis[s3];
        uint2 u0 = *(const uint2*)(A2 + (long long)s0 * 128 + fl * 4);
        uint2 u1 = *(const uint2*)(A2 + (long long)s1 * 128 + fl * 4);
        uint2 u2 = *(const uint2*)(A2 + (long long)s2 * 128 + fl * 4);
        uint2 u3 = *(const uint2*)(A2 + (long long)s3 * 128 + fl * 4);
        w0 *= dn; w1 *= dn; w2 *= dn; w3 *= dn;
        a0 = fmaf(w0, bfl(u0.x), a0); a1 = fmaf(w0, bfh(u0.x), a1);
        a2 = fmaf(w0, bfl(u0.y), a2); a3 = fmaf(w0, bfh(u0.y), a3);
        a0 = fmaf(w1, bfl(u1.x), a0); a1 = fmaf(w1, bfh(u1.x), a1);
        a2 = fmaf(w1, bfl(u1.y), a2); a3 = fmaf(w1, bfh(u1.y), a3);
        a0 = fmaf(w2, bfl(u2.x), a0); a1 = fmaf(w2, bfh(u2.x), a1);
        a2 = fmaf(w2, bfl(u2.y), a2); a3 = fmaf(w2, bfh(u2.y), a3);
        a0 = fmaf(w3, bfl(u3.x), a0); a1 = fmaf(w3, bfh(u3.x), a1);
        a2 = fmaf(w3, bfl(u3.y), a2); a3 = fmaf(w3, bfh(u3.y), a3);
    }
    for (; e < end; ++e) {
        int s = csr_at<SMALLN>(csr, e);
        float w = dis[s] * dn;
        uint2 u = *(const uint2*)(A2 + (long long)s * 128 + fl * 4);
        a0 = fmaf(w, bfl(u.x), a0); a1 = fmaf(w, bfh(u.x), a1);
        a2 = fmaf(w, bfl(u.y), a2); a3 = fmaf(w, bfh(u.y), a3);
    }
    const float4 b = *(const float4*)&bias[fl * 4];
    float4 o;
    o.x = fmaxf(a0 + b.x, 0.f);
    o.y = fmaxf(a1 + b.y, 0.f);
    o.z = fmaxf(a2 + b.z, 0.f);
    o.w = fmaxf(a3 + b.w, 0.f);
    *(float4*)(outC + (long long)n * 128 + fl * 4) = o;
}

// ---------------- Pool (batch sorted): 32-node strips, pre-reduced atomic flush -------

#define PSTRIP 32
__global__ __launch_bounds__(128) void gnn_pool(const float* __restrict__ h,
                                                const int* __restrict__ batch,
                                                const int* __restrict__ flags,
                                                float* __restrict__ pooled, int N, int B) {
    int i64 = flags[1];
    int f = threadIdx.x;
    int n0 = blockIdx.x * PSTRIP;
    if (n0 >= N) return;
    int nend = min(n0 + PSTRIP, N);
    int cur = clampi(ld_idx(batch, n0, i64), 0, B - 1);
    float acc = 0.0f;
    for (int n = n0; n < nend; ++n) {
        int b = clampi(ld_idx(batch, n, i64), 0, B - 1);
        if (b != cur) {
            atomicAdd(&pooled[cur * 128 + f], acc);
            acc = 0.0f; cur = b;
        }
        acc += h[(long long)n * 128 + f];
    }
    atomicAdd(&pooled[cur * 128 + f], acc);
}

// ---------------- head: mean (cnt via binary search) + MLP ----------------

__global__ __launch_bounds__(128) void gnn_head(const float* __restrict__ pooled,
                                                const int* __restrict__ batch,
                                                const float* __restrict__ W3,
                                                const float* __restrict__ b3,
                                                const float* __restrict__ W4,
                                                const float* __restrict__ b4,
                                                const int* __restrict__ flags,
                                                void* __restrict__ outv, int N) {
    __shared__ float xs[128];
    __shared__ float rs[128];
    __shared__ float cinv;
    int b = blockIdx.x, f = threadIdx.x;
    if (f == 0) {
        int i64 = flags[1];
        int L = 0, R = N;
        while (L < R) { int m = (L + R) >> 1; if (ld_idx(batch, m, i64) < b) L = m + 1; else R = m; }
        int lo = L;
        L = 0; R = N;
        while (L < R) { int m = (L + R) >> 1; if (ld_idx(batch, m, i64) < b + 1) L = m + 1; else R = m; }
        cinv = 1.0f / fmaxf((float)(L - lo), 1.0f);
    }
    __syncthreads();
    xs[f] = pooled[b * 128 + f] * cinv;
    __syncthreads();
    float acc = b3[f];
    for (int k = 0; k < 128; ++k) acc = fmaf(xs[k], W3[k * 128 + f], acc);
    rs[f] = fmaxf(acc, 0.f);
    __syncthreads();
    if (f < 64) {
        float a2 = b4[f];
        for (int k = 0; k < 128; ++k) a2 = fmaf(rs[k], W4[k * 64 + f], a2);
        if (flags[0]) ((float*)outv)[b * 64 + f] = a2;
        else          ((unsigned short*)outv)[b * 64 + f] = f2bf(a2);
    }
}

// ---------------- Launch ----------------

extern "C" void kernel_launch(void* const* d_in, const int* in_sizes, int n_in,
                              void* d_out, int out_size, void* d_ws, size_t ws_size,
                              hipStream_t stream) {
    const void* x  = d_in[0];
    const int* ei  = (const int*)d_in[1];
    const int* bat = (const int*)d_in[2];

    const int N = in_sizes[0] / 64;    // 50000
    const int E = in_sizes[1] / 2;     // 800000
    const int B = out_size / 64;       // 64
    const bool smalln = (N < 65536);

    char* p = (char*)d_ws;
    auto alloc = [&](size_t bytes) { void* q = (void*)p; p += (bytes + 255) & ~(size_t)255; return q; };
    int*   flags    = (int*)alloc(256);
    float* wsW      = (float*)alloc((size_t)OTOT * 4);
    int*   degcnt   = (int*)alloc((size_t)N * 4);
    float* dis      = (float*)alloc((size_t)N * 4);
    int*   excl     = (int*)alloc((size_t)N * 4);
    int*   bsums    = (int*)alloc(1024);
    int*   rank     = (int*)alloc((size_t)E * 4);
    void*  csr      = alloc((size_t)E * (smalln ? 2 : 4));
    unsigned short* xb = (unsigned short*)alloc((size_t)N * 64 * 2);
    float* H1       = (float*)alloc((size_t)N * 128 * 4);
    float* C2       = (float*)alloc((size_t)N * 128 * 4);
    unsigned short* A2 = (unsigned short*)alloc((size_t)N * 128 * 2);
    float* pooled   = (float*)alloc((size_t)B * 128 * 4);
    (void)ws_size; (void)n_in;

    const int nbN = (N + 255) / 256;   // 196 (fits single-block scan2)

    gnn_prep<<<512, 256, 0, stream>>>(d_in[3], d_in[4], d_in[5], d_in[6],
                                      d_in[7], d_in[8], d_in[9], d_in[10],
                                      x, ei, flags, degcnt, pooled, wsW, xb, N, B);

    gnn_hist<<<(E + 1023) / 1024, 256, 0, stream>>>(ei, E, N, flags, degcnt, rank);
    gnn_scan1<<<nbN, 256, 0, stream>>>(degcnt, excl, bsums, dis, N);
    gnn_scan2<<<1, 256, 0, stream>>>(bsums, nbN);
    if (smalln)
        gnn_fill<true><<<(E + 255) / 256, 256, 0, stream>>>(ei, excl, bsums, rank, csr, E, N, flags);
    else
        gnn_fill<false><<<(E + 255) / 256, 256, 0, stream>>>(ei, excl, bsums, rank, csr, E, N, flags);

    const int nlin = (N + 15) / 16;    // 16-node blocks, 128 threads
    const int nagg = (N + 7) / 8;

    // layer 1 (fused): H1 = relu((A_hat @ x) @ W1 + b1)
    if (smalln)
        gnn_aggx_lin1<true><<<nlin, 128, 0, stream>>>(x, xb, excl, bsums, csr, dis, flags,
                                                      wsW + OW1, wsW + OB1, N, E, H1);
    else
        gnn_aggx_lin1<false><<<nlin, 128, 0, stream>>>(x, xb, excl, bsums, csr, dis, flags,
                                                       wsW + OW1, wsW + OB1, N, E, H1);

    // layer 2: A2 = H1 @ W2 (bf16) ; C2 = relu(A_hat @ A2 + b2)
    gnn_linear<128, false, true><<<nlin, 128, 0, stream>>>(H1, wsW + OW2, wsW + OB2, N, (void*)A2);
    if (smalln)
        gnn_agg_bf<true><<<nagg, 256, 0, stream>>>(A2, excl, bsums, csr, dis, wsW + OB2, C2, N, E);
    else
        gnn_agg_bf<false><<<nagg, 256, 0, stream>>>(A2, excl, bsums, csr, dis, wsW + OB2, C2, N, E);

    // pool + head
    gnn_pool<<<(N + PSTRIP - 1) / PSTRIP, 128, 0, stream>>>(C2, bat, flags, pooled, N, B);
    gnn_head<<<B, 128, 0, stream>>>(pooled, bat, wsW + OW3, wsW + OB3,
                                    wsW + OW4, wsW + OB4, flags, d_out, N);
}